// Round 6
// baseline (194.607 us; speedup 1.0000x reference)
//
#include <hip/hip_runtime.h>

// GAT: B=256, N=64, K=12, D=128
// Algebra: wq_eff = Wq @ wa_q, wk_eff = Wk @ wa_k; V-projection commutes
// with the attention average: out = h_bar @ Wv + bv * (sum attn).
//
// R5 (resubmit; previous round hit a GPU-acquisition timeout, never ran):
// depth-2 register pipeline (R4 post-mortem: VGPR=64 = allocator stopped
// at the occupancy step and erased half the pipeline; R2-vs-R4 proved TLP
// doesn't help but pipeline depth does):
//  - THREE statically-named pair buffers (A,B,C), rotation fully unrolled:
//    prologue loads A,B,C; loop issues A' while computing — 14-16 loads in
//    flight during compute (vs 7 in R4).
//  - mask loads for all 4 pairs hoisted to prologue (steady state has zero
//    scalar loads).
//  - VGPR target ~120: inside the 65-128 tier R4 already occupies (16
//    waves/CU), so depth-2 costs no occupancy. launch_bounds(256,4) caps 128.
//  - asm "+v" pins after the dots (R4's fix) kept: no re-loads for pooling.
//  - Phase B unchanged (b128 row-quads, 2 rows/thread).

#define B_  256
#define N_  64
#define K_  12
#define D_  128
#define BN  (B_ * N_)          // 16384 (b,n) pairs
#define ROWS 16                // pairs per block; wave owns 4
#define HB_STRIDE 132          // 528B rows: 16B-aligned

#define PIN4(v)  asm volatile("" : "+v"(v.x), "+v"(v.y), "+v"(v.z), "+v"(v.w))

// ws float layout: [0..127] wq_eff | [128..255] wk_eff | [256] cq | [257] ckb
// ---------------------------------------------------------------------------
__global__ void prep_kernel(const float* __restrict__ Wq, const float* __restrict__ bq,
                            const float* __restrict__ Wk, const float* __restrict__ bk,
                            const float* __restrict__ wa_q, const float* __restrict__ wa_k,
                            float* __restrict__ ws) {
    int g = blockIdx.x;
    int l = threadIdx.x;
    const float* row;
    const float* wa;
    float* outp;
    if (g < 128)      { row = Wq + g * D_;         wa = wa_q; outp = ws + g; }
    else if (g < 256) { row = Wk + (g - 128) * D_; wa = wa_k; outp = ws + 128 + (g - 128); }
    else if (g == 256){ row = bq;                  wa = wa_q; outp = ws + 256; }
    else              { row = bk;                  wa = wa_k; outp = ws + 257; }

    float2 r = ((const float2*)row)[l];
    float2 w = ((const float2*)wa)[l];
    float p = r.x * w.x + r.y * w.y;
    #pragma unroll
    for (int m = 1; m < 64; m <<= 1) p += __shfl_xor(p, m, 64);
    if (l == 0) *outp = p;
}

// ---------------------------------------------------------------------------
// grid = BN/16 = 1024 blocks x 256 threads. Block owns 16 pairs; wave owns 4.
// Lane l: half h=l>>5 covers neighbor slots {1+2i+h}; li=l&31 owns features
// 4li..4li+3. After 3 RS + 2 finish stages lane (l&7) holds one full dot.
__global__ void __launch_bounds__(256, 4)
fused_kernel(const float* __restrict__ nodes, const float* __restrict__ neigh,
             const float* __restrict__ mask, const float* __restrict__ ba_p,
             const float* __restrict__ ws, const float* __restrict__ Wv,
             const float* __restrict__ bv, float* __restrict__ out) {
    __shared__ float hb[ROWS * HB_STRIDE];
    __shared__ float scL[ROWS];

    const int t    = threadIdx.x;
    const int wave = t >> 6;
    const int l    = t & 63;
    const int li   = l & 31;
    const int h    = l >> 5;
    const int j8   = l & 7;

    const float cq  = ws[256];
    const float ckb = ws[257];
    const float ba  = ba_p[0];
    const float cst = cq + ckb + ba;
    const float4 wqe4 = ((const float4*)ws)[li];          // wq_eff[4li..]
    const float4 wke4 = ((const float4*)(ws + 128))[li];  // wk_eff[4li..]

    const int idx0 = blockIdx.x * ROWS + wave * 4;

    // ---- prologue: all 4 masks + pair buffers A(=p0), B(=p1), C(=p2) ----
    float mv0 = (j8 < 6) ? mask[(size_t)(idx0 + 0) * K_ + 2 * j8 + h] : 0.0f;
    float mv1 = (j8 < 6) ? mask[(size_t)(idx0 + 1) * K_ + 2 * j8 + h] : 0.0f;
    float mv2 = (j8 < 6) ? mask[(size_t)(idx0 + 2) * K_ + 2 * j8 + h] : 0.0f;
    float mv3 = (j8 < 6) ? mask[(size_t)(idx0 + 3) * K_ + 2 * j8 + h] : 0.0f;

    float4 xbA[6], xbB[6], xbC[6];
    float4 nvA, nvB, nvC;

    #define LOADP(XB, NV, pi) do {                                              \
        const int idx_ = idx0 + (pi);                                           \
        NV = ((const float4*)(nodes + (size_t)idx_ * D_))[li];                  \
        const float4* gp_ = (const float4*)(neigh + (size_t)idx_ * (K_ * D_));  \
        XB[0] = gp_[0 * 64 + l];                                                \
        XB[1] = gp_[1 * 64 + l];                                                \
        XB[2] = gp_[2 * 64 + l];                                                \
        XB[3] = gp_[3 * 64 + l];                                                \
        XB[4] = gp_[4 * 64 + l];                                                \
        XB[5] = gp_[5 * 64 + l];                                                \
    } while (0)

    // Full attention chain for one pair held in (XB, NV, MV); writes hb row I.
    #define COMPUTE(XB, NV, MV, I) do {                                         \
        float v0 = XB[0].x*wke4.x + XB[0].y*wke4.y + XB[0].z*wke4.z + XB[0].w*wke4.w; \
        float v1 = XB[1].x*wke4.x + XB[1].y*wke4.y + XB[1].z*wke4.z + XB[1].w*wke4.w; \
        float v2 = XB[2].x*wke4.x + XB[2].y*wke4.y + XB[2].z*wke4.z + XB[2].w*wke4.w; \
        float v3 = XB[3].x*wke4.x + XB[3].y*wke4.y + XB[3].z*wke4.z + XB[3].w*wke4.w; \
        float v4 = XB[4].x*wke4.x + XB[4].y*wke4.y + XB[4].z*wke4.z + XB[4].w*wke4.w; \
        float v5 = XB[5].x*wke4.x + XB[5].y*wke4.y + XB[5].z*wke4.z + XB[5].w*wke4.w; \
        float v6 = NV.x*wke4.x + NV.y*wke4.y + NV.z*wke4.z + NV.w*wke4.w;       \
        float v7 = NV.x*wqe4.x + NV.y*wqe4.y + NV.z*wqe4.z + NV.w*wqe4.w;       \
        PIN4(XB[0]); PIN4(XB[1]); PIN4(XB[2]);                                  \
        PIN4(XB[3]); PIN4(XB[4]); PIN4(XB[5]); PIN4(NV);                        \
        float A0, A1, A2, A3;                                                   \
        {                                                                       \
            const bool hi_ = (l & 1);                                           \
            float g0 = hi_ ? v0 : v1;                                           \
            float g1 = hi_ ? v2 : v3;                                           \
            float g2 = hi_ ? v4 : v5;                                           \
            float g3 = hi_ ? v6 : v7;                                           \
            g0 = __shfl_xor(g0, 1, 64);                                         \
            g1 = __shfl_xor(g1, 1, 64);                                         \
            g2 = __shfl_xor(g2, 1, 64);                                         \
            g3 = __shfl_xor(g3, 1, 64);                                         \
            A0 = (hi_ ? v1 : v0) + g0;                                          \
            A1 = (hi_ ? v3 : v2) + g1;                                          \
            A2 = (hi_ ? v5 : v4) + g2;                                          \
            A3 = (hi_ ? v7 : v6) + g3;                                          \
        }                                                                       \
        float B0, B1;                                                           \
        {                                                                       \
            const bool hi_ = (l & 2);                                           \
            float g0 = hi_ ? A0 : A1;                                           \
            float g1 = hi_ ? A2 : A3;                                           \
            g0 = __shfl_xor(g0, 2, 64);                                         \
            g1 = __shfl_xor(g1, 2, 64);                                         \
            B0 = (hi_ ? A1 : A0) + g0;                                          \
            B1 = (hi_ ? A3 : A2) + g1;                                          \
        }                                                                       \
        float c;                                                                \
        {                                                                       \
            const bool hi_ = (l & 4);                                           \
            float g = hi_ ? B0 : B1;                                            \
            g = __shfl_xor(g, 4, 64);                                           \
            c = (hi_ ? B1 : B0) + g;                                            \
        }                                                                       \
        c += __shfl_xor(c, 8, 64);                                              \
        c += __shfl_xor(c, 16, 64);                                             \
        const float pq_  = __shfl(c, 7, 8);                                     \
        const float pkn_ = __shfl(c, 6, 8);                                     \
        const float base_ = pq_ + cst;                                          \
        float s0_ = base_ + pkn_;                                               \
        s0_ = (s0_ >= 0.0f) ? s0_ : 0.2f * s0_;                                 \
        const float e0_ = __expf(s0_);                                          \
        float sj_ = base_ + c;                                                  \
        sj_ = (sj_ >= 0.0f) ? sj_ : 0.2f * sj_;                                 \
        const float ej_ = (j8 < 6) ? __expf(sj_) * (MV) : 0.0f;                 \
        const float an_ = (h == 0) ? e0_ : 0.0f;                                \
        float ax = an_ * NV.x, ay = an_ * NV.y;                                 \
        float az = an_ * NV.z, aw = an_ * NV.w;                                 \
        float Se_ = 0.0f;                                                       \
        _Pragma("unroll")                                                       \
        for (int q_ = 0; q_ < 6; ++q_) {                                        \
            const float bi_ = __shfl(ej_, q_, 8);                               \
            ax += bi_ * XB[q_].x;                                               \
            ay += bi_ * XB[q_].y;                                               \
            az += bi_ * XB[q_].z;                                               \
            aw += bi_ * XB[q_].w;                                               \
            Se_ += bi_;                                                         \
        }                                                                       \
        ax += __shfl_xor(ax, 32, 64);                                           \
        ay += __shfl_xor(ay, 32, 64);                                           \
        az += __shfl_xor(az, 32, 64);                                           \
        aw += __shfl_xor(aw, 32, 64);                                           \
        Se_ += __shfl_xor(Se_, 32, 64);                                         \
        const float S_   = e0_ + Se_;                                           \
        const float inv_ = 1.0f / (S_ + 1e-16f);                                \
        if (h == 0) {                                                           \
            const int lrow_ = wave * 4 + (I);                                   \
            float4 o_;                                                          \
            o_.x = ax * inv_;                                                   \
            o_.y = ay * inv_;                                                   \
            o_.z = az * inv_;                                                   \
            o_.w = aw * inv_;                                                   \
            *(float4*)(hb + lrow_ * HB_STRIDE + 4 * li) = o_;                   \
            if (li == 0) scL[lrow_] = S_ * inv_;                                \
        }                                                                       \
    } while (0)

    LOADP(xbA, nvA, 0);
    LOADP(xbB, nvB, 1);
    LOADP(xbC, nvC, 2);
    __builtin_amdgcn_sched_barrier(0);
    COMPUTE(xbA, nvA, mv0, 0);              // B, C in flight (14 loads)
    __builtin_amdgcn_sched_barrier(0);
    LOADP(xbA, nvA, 3);                     // reuse A's registers for pair 3
    __builtin_amdgcn_sched_barrier(0);
    COMPUTE(xbB, nvB, mv1, 1);              // C, A' in flight
    __builtin_amdgcn_sched_barrier(0);
    COMPUTE(xbC, nvC, mv2, 2);              // A' in flight
    COMPUTE(xbA, nvA, mv3, 3);              // tail

    #undef LOADP
    #undef COMPUTE
    __syncthreads();

    // ---- Phase B: out[16x128] = hb @ Wv + bv * scale ----
    // thread (rg=t>>5, cg=t&31) does rows {rg, rg+8}, cols 4cg..4cg+3.
    const int rg = t >> 5;
    const int cg = t & 31;
    const float4* wv4 = (const float4*)Wv;        // [k][32] of float4
    const float* hr0 = hb + rg * HB_STRIDE;
    const float* hr1 = hb + (rg + 8) * HB_STRIDE;

    float4 acc0 = make_float4(0.0f, 0.0f, 0.0f, 0.0f);
    float4 acc1 = make_float4(0.0f, 0.0f, 0.0f, 0.0f);
    #pragma unroll 8
    for (int kq = 0; kq < 32; ++kq) {
        const float4 a0 = *(const float4*)(hr0 + 4 * kq);
        const float4 a1 = *(const float4*)(hr1 + 4 * kq);
        #pragma unroll
        for (int e = 0; e < 4; ++e) {
            const float4 w = wv4[(4 * kq + e) * 32 + cg];
            const float f0 = (e == 0) ? a0.x : (e == 1) ? a0.y : (e == 2) ? a0.z : a0.w;
            const float f1 = (e == 0) ? a1.x : (e == 1) ? a1.y : (e == 2) ? a1.z : a1.w;
            acc0.x += f0 * w.x; acc0.y += f0 * w.y;
            acc0.z += f0 * w.z; acc0.w += f0 * w.w;
            acc1.x += f1 * w.x; acc1.y += f1 * w.y;
            acc1.z += f1 * w.z; acc1.w += f1 * w.w;
        }
    }

    const float4 bvv = ((const float4*)bv)[cg];
    const int row0 = blockIdx.x * ROWS;
    {
        const float s = scL[rg];
        float4 o;
        o.x = acc0.x + bvv.x * s;
        o.y = acc0.y + bvv.y * s;
        o.z = acc0.z + bvv.z * s;
        o.w = acc0.w + bvv.w * s;
        *(float4*)(out + (size_t)(row0 + rg) * D_ + cg * 4) = o;
    }
    {
        const float s = scL[rg + 8];
        float4 o;
        o.x = acc1.x + bvv.x * s;
        o.y = acc1.y + bvv.y * s;
        o.z = acc1.z + bvv.z * s;
        o.w = acc1.w + bvv.w * s;
        *(float4*)(out + (size_t)(row0 + rg + 8) * D_ + cg * 4) = o;
    }
}

// ---------------------------------------------------------------------------
extern "C" void kernel_launch(void* const* d_in, const int* in_sizes, int n_in,
                              void* d_out, int out_size, void* d_ws, size_t ws_size,
                              hipStream_t stream) {
    const float* nodes = (const float*)d_in[0];
    const float* neigh = (const float*)d_in[1];
    const float* mask  = (const float*)d_in[2];
    const float* Wq    = (const float*)d_in[3];
    const float* bq    = (const float*)d_in[4];
    const float* Wk    = (const float*)d_in[5];
    const float* bk    = (const float*)d_in[6];
    const float* Wv    = (const float*)d_in[7];
    const float* bv    = (const float*)d_in[8];
    const float* wa_q  = (const float*)d_in[9];
    const float* wa_k  = (const float*)d_in[10];
    const float* ba    = (const float*)d_in[11];
    float* out = (float*)d_out;
    float* ws  = (float*)d_ws;

    prep_kernel<<<258, 64, 0, stream>>>(Wq, bq, Wk, bk, wa_q, wa_k, ws);
    fused_kernel<<<BN / ROWS, 256, 0, stream>>>(nodes, neigh, mask, ba, ws, Wv, bv, out);
}